// Round 6
// baseline (1578.652 us; speedup 1.0000x reference)
//
#include <hip/hip_runtime.h>

#define NN 100000
#define NE 3200000
#define DD 64

constexpr int ELEMS = NN * DD;            // 6,400,000
constexpr int NB    = (NN + 1023) / 1024; // 98 scan blocks
constexpr int NBK   = (NN + 255) / 256;   // 391 buckets of 256 nodes

// ---------------- Threefry-2x32, key = (0, 42), 20 rounds ----------------
__device__ __forceinline__ void threefry2x32_0_42(unsigned int c0, unsigned int c1,
                                                  unsigned int& o0, unsigned int& o1) {
  const unsigned int ks0 = 0u;
  const unsigned int ks1 = 42u;
  const unsigned int ks2 = ks0 ^ ks1 ^ 0x1BD11BDAu;
  unsigned int x0 = c0 + ks0;
  unsigned int x1 = c1 + ks1;
#define TF_R(r) { x0 += x1; x1 = (x1 << (r)) | (x1 >> (32 - (r))); x1 ^= x0; }
  TF_R(13) TF_R(15) TF_R(26) TF_R(6)
  x0 += ks1; x1 += ks2 + 1u;
  TF_R(17) TF_R(29) TF_R(16) TF_R(24)
  x0 += ks2; x1 += ks0 + 2u;
  TF_R(13) TF_R(15) TF_R(26) TF_R(6)
  x0 += ks0; x1 += ks1 + 3u;
  TF_R(17) TF_R(29) TF_R(16) TF_R(24)
  x0 += ks1; x1 += ks2 + 4u;
  TF_R(13) TF_R(15) TF_R(26) TF_R(6)
  x0 += ks2; x1 += ks0 + 5u;
#undef TF_R
  o0 = x0; o1 = x1;
}

__device__ __forceinline__ bool keep_from_bits(unsigned int bits) {
  float f = __uint_as_float((bits >> 9) | 0x3f800000u) - 1.0f;
  return f < 0.9f;
}

// ---------------- A: h = sign(x); h0f = tanh(x) ----------------
__global__ void kA(const float* __restrict__ x,
                   float* __restrict__ h_out,
                   float* __restrict__ h0f) {
  int i = blockIdx.x * blockDim.x + threadIdx.x;
  if (i >= ELEMS) return;
  float xv = x[i];
  h0f[i] = (float)tanh((double)xv);
  h_out[i] = (xv > 0.0f) ? 1.0f : ((xv < 0.0f) ? -1.0f : 0.0f);
}

// ---------------- degree histogram over dst ----------------
__global__ void k_hist(const int* __restrict__ dst, int* __restrict__ deg) {
  int e = blockIdx.x * blockDim.x + threadIdx.x;
  if (e >= NE) return;
  atomicAdd(&deg[dst[e]], 1);
}

// ---------------- scan step 1: per-block inclusive scan (1024) ----------------
__global__ void k_scan1(const int* __restrict__ deg,
                        int* __restrict__ tmp, int* __restrict__ bsum) {
  __shared__ int s[1024];
  int t = threadIdx.x;
  int i = blockIdx.x * 1024 + t;
  s[t] = (i < NN) ? deg[i] : 0;
  __syncthreads();
  for (int off = 1; off < 1024; off <<= 1) {
    int add = (t >= off) ? s[t - off] : 0;
    __syncthreads();
    s[t] += add;
    __syncthreads();
  }
  if (i < NN) tmp[i] = s[t];
  if (t == 1023) bsum[blockIdx.x] = s[t];
}

// ---------------- scan step 2: exclusive-scan the 98 block sums ----------------
__global__ void k_scan2(int* __restrict__ bsum) {
  if (blockIdx.x == 0 && threadIdx.x == 0) {
    int run = 0;
    for (int b = 0; b < NB; ++b) { int v = bsum[b]; bsum[b] = run; run += v; }
  }
}

// ---------------- scan step 3: rowptr ----------------
__global__ void k_scan3(const int* __restrict__ tmp, const int* __restrict__ bsum,
                        int* __restrict__ rowptr) {
  int t = threadIdx.x;
  int i = blockIdx.x * 1024 + t;
  if (i >= NN) return;
  rowptr[i + 1] = tmp[i] + bsum[blockIdx.x];
  if (i == 0) rowptr[0] = 0;
}

// ---------------- bucket cursor init: bcur[b] = rowptr[b<<8] ----------------
__global__ void k_binit(const int* __restrict__ rowptr, int* __restrict__ bcur) {
  int b = blockIdx.x * blockDim.x + threadIdx.x;
  if (b < NBK) bcur[b] = rowptr[b << 8];
}

// ---------------- bucket scatter: pack (src<<8)|(dst&255) into bucket region ----------------
__global__ void k_bscatter(const int* __restrict__ src, const int* __restrict__ dst,
                           int* __restrict__ bcur, unsigned int* __restrict__ ebuf) {
  int e = blockIdx.x * blockDim.x + threadIdx.x;
  if (e >= NE) return;
  int d = dst[e];
  int b = d >> 8;
  int pos = atomicAdd(&bcur[b], 1);
  ebuf[pos] = ((unsigned int)src[e] << 8) | (unsigned int)(d & 255);
}

// ---------------- bucket fill: LDS per-node cursors, local csr writes ----------------
__global__ void k_bfill(const int* __restrict__ rowptr, const unsigned int* __restrict__ ebuf,
                        int* __restrict__ csr_src) {
  __shared__ int cur[256];
  int b = blockIdx.x;
  int t = threadIdx.x;
  int nfirst = b << 8;
  int ncount = min(256, NN - nfirst);
  if (t < ncount) cur[t] = rowptr[nfirst + t];
  __syncthreads();
  int beg = rowptr[nfirst];
  int end = rowptr[nfirst + ncount];
  for (int j = beg + t; j < end; j += blockDim.x) {
    unsigned int v = ebuf[j];
    int pos = atomicAdd(&cur[v & 255u], 1);
    csr_src[pos] = (int)(v >> 8);
  }
}

// ---------------- G1: per-node gather, exact f64 accumulate, sign -> int8 ----------------
__global__ void k_gather1(const int* __restrict__ rowptr, const int* __restrict__ csr_src,
                          const float* __restrict__ h0f, signed char* __restrict__ h1) {
  int g = blockIdx.x * blockDim.x + threadIdx.x;
  int n = g >> 6;
  int lane = g & 63;
  if (n >= NN) return;
  int beg = rowptr[n], end = rowptr[n + 1];
  double acc = (double)h0f[n * DD + lane];  // self-loop
  int j = beg;
  for (; j + 4 <= end; j += 4) {
    int s0 = csr_src[j], s1 = csr_src[j + 1], s2 = csr_src[j + 2], s3 = csr_src[j + 3];
    float v0 = h0f[s0 * DD + lane];
    float v1 = h0f[s1 * DD + lane];
    float v2 = h0f[s2 * DD + lane];
    float v3 = h0f[s3 * DD + lane];
    acc += (double)v0; acc += (double)v1; acc += (double)v2; acc += (double)v3;
  }
  for (; j < end; ++j) acc += (double)h0f[csr_src[j] * DD + lane];
  h1[n * DD + lane] = (acc > 0.0) ? 1 : ((acc < 0.0) ? -1 : 0);
}

// ---------------- G2: per-node int gather + sign + partitionable-threefry dropout ----------------
__global__ void k_gather2(const int* __restrict__ rowptr, const int* __restrict__ csr_src,
                          const signed char* __restrict__ h1, float* __restrict__ out2) {
  int g = blockIdx.x * blockDim.x + threadIdx.x;
  int n = g >> 6;
  int lane = g & 63;
  if (n >= NN) return;
  int beg = rowptr[n], end = rowptr[n + 1];
  int acc = (int)h1[n * DD + lane];  // self-loop
  int j = beg;
  for (; j + 4 <= end; j += 4) {
    int s0 = csr_src[j], s1 = csr_src[j + 1], s2 = csr_src[j + 2], s3 = csr_src[j + 3];
    acc += (int)h1[s0 * DD + lane] + (int)h1[s1 * DD + lane]
         + (int)h1[s2 * DD + lane] + (int)h1[s3 * DD + lane];
  }
  for (; j < end; ++j) acc += (int)h1[csr_src[j] * DD + lane];

  int i = n * DD + lane;
  float s = (acc > 0) ? 1.0f : ((acc < 0) ? -1.0f : 0.0f);
  unsigned int o0, o1;
  threefry2x32_0_42(0u, (unsigned int)i, o0, o1);
  unsigned int bits = o0 ^ o1;
  const float inv_keep = 1.0f / 0.9f;
  out2[i] = keep_from_bits(bits) ? s * inv_keep : 0.0f;
}

extern "C" void kernel_launch(void* const* d_in, const int* in_sizes, int n_in,
                              void* d_out, int out_size, void* d_ws, size_t ws_size,
                              hipStream_t stream) {
  const float* x   = (const float*)d_in[0];
  const int*   ei  = (const int*)d_in[1];
  const int*   src = ei;        // edge_index[0]
  const int*   dst = ei + NE;   // edge_index[1]

  float* out_h  = (float*)d_out;           // output 0: h    [ELEMS]
  float* out_h2 = (float*)d_out + ELEMS;   // output 1: h_2  [ELEMS]

  char* ws = (char*)d_ws;
  float*        h0f     = (float*)ws;                              // 25.6 MB @ 0
  signed char*  h1      = (signed char*)(ws + ((size_t)26 << 20)); // 6.4 MB  @ 26M
  int*          deg     = (int*)(ws + ((size_t)33 << 20));         // 400 KB
  int*          tmp     = (int*)(ws + ((size_t)34 << 20));         // 400 KB
  int*          bsum    = (int*)(ws + ((size_t)35 << 20));         // <1 KB
  int*          rowptr  = (int*)(ws + ((size_t)36 << 20));         // 400 KB + 4
  int*          bcur    = (int*)(ws + ((size_t)37 << 20));         // ~1.6 KB
  int*          csr_src = (int*)(ws + ((size_t)38 << 20));         // 12.8 MB
  unsigned int* ebuf    = (unsigned int*)(ws + ((size_t)51 << 20));// 12.8 MB

  const int B = 256;
  const int gElems = (ELEMS + B - 1) / B;          // 25000
  const int gEdges = (NE + B - 1) / B;             // 12500

  (void)hipMemsetAsync(deg, 0, (size_t)NN * sizeof(int), stream);

  kA<<<gElems, B, 0, stream>>>(x, out_h, h0f);

  k_hist<<<gEdges, B, 0, stream>>>(dst, deg);
  k_scan1<<<NB, 1024, 0, stream>>>(deg, tmp, bsum);
  k_scan2<<<1, 64, 0, stream>>>(bsum);
  k_scan3<<<NB, 1024, 0, stream>>>(tmp, bsum, rowptr);

  k_binit<<<(NBK + B - 1) / B, B, 0, stream>>>(rowptr, bcur);
  k_bscatter<<<gEdges, B, 0, stream>>>(src, dst, bcur, ebuf);
  k_bfill<<<NBK, B, 0, stream>>>(rowptr, ebuf, csr_src);

  k_gather1<<<gElems, B, 0, stream>>>(rowptr, csr_src, h0f, h1);
  k_gather2<<<gElems, B, 0, stream>>>(rowptr, csr_src, h1, out_h2);
}

// Round 7
// 499.376 us; speedup vs baseline: 3.1612x; 3.1612x over previous
//
#include <hip/hip_runtime.h>

#define NN 100000
#define NE 3200000
#define DD 64

constexpr int ELEMS = NN * DD;            // 6,400,000
constexpr int NB    = (NN + 1023) / 1024; // 98 scan blocks
constexpr int NBK   = (NN + 255) / 256;   // 391 buckets of 256 nodes
constexpr int NBLK  = 512;                // partition blocks
constexpr int EPB   = NE / NBLK;          // 6250 edges per block (exact)

// ---------------- Threefry-2x32, key = (0, 42), 20 rounds ----------------
__device__ __forceinline__ void threefry2x32_0_42(unsigned int c0, unsigned int c1,
                                                  unsigned int& o0, unsigned int& o1) {
  const unsigned int ks0 = 0u;
  const unsigned int ks1 = 42u;
  const unsigned int ks2 = ks0 ^ ks1 ^ 0x1BD11BDAu;
  unsigned int x0 = c0 + ks0;
  unsigned int x1 = c1 + ks1;
#define TF_R(r) { x0 += x1; x1 = (x1 << (r)) | (x1 >> (32 - (r))); x1 ^= x0; }
  TF_R(13) TF_R(15) TF_R(26) TF_R(6)
  x0 += ks1; x1 += ks2 + 1u;
  TF_R(17) TF_R(29) TF_R(16) TF_R(24)
  x0 += ks2; x1 += ks0 + 2u;
  TF_R(13) TF_R(15) TF_R(26) TF_R(6)
  x0 += ks0; x1 += ks1 + 3u;
  TF_R(17) TF_R(29) TF_R(16) TF_R(24)
  x0 += ks1; x1 += ks2 + 4u;
  TF_R(13) TF_R(15) TF_R(26) TF_R(6)
  x0 += ks2; x1 += ks0 + 5u;
#undef TF_R
  o0 = x0; o1 = x1;
}

__device__ __forceinline__ bool keep_from_bits(unsigned int bits) {
  float f = __uint_as_float((bits >> 9) | 0x3f800000u) - 1.0f;
  return f < 0.9f;
}

// ---------------- A: h = sign(x); h0f = tanh(x) ----------------
__global__ void kA(const float* __restrict__ x,
                   float* __restrict__ h_out,
                   float* __restrict__ h0f) {
  int i = blockIdx.x * blockDim.x + threadIdx.x;
  if (i >= ELEMS) return;
  float xv = x[i];
  h0f[i] = (float)tanh((double)xv);
  h_out[i] = (xv > 0.0f) ? 1.0f : ((xv < 0.0f) ? -1.0f : 0.0f);
}

// ---------------- degree histogram over dst (for rowptr) ----------------
__global__ void k_hist(const int* __restrict__ dst, int* __restrict__ deg) {
  int e = blockIdx.x * blockDim.x + threadIdx.x;
  if (e >= NE) return;
  atomicAdd(&deg[dst[e]], 1);
}

// ---------------- scan step 1: per-block inclusive scan (1024) ----------------
__global__ void k_scan1(const int* __restrict__ deg,
                        int* __restrict__ tmp, int* __restrict__ bsum) {
  __shared__ int s[1024];
  int t = threadIdx.x;
  int i = blockIdx.x * 1024 + t;
  s[t] = (i < NN) ? deg[i] : 0;
  __syncthreads();
  for (int off = 1; off < 1024; off <<= 1) {
    int add = (t >= off) ? s[t - off] : 0;
    __syncthreads();
    s[t] += add;
    __syncthreads();
  }
  if (i < NN) tmp[i] = s[t];
  if (t == 1023) bsum[blockIdx.x] = s[t];
}

// ---------------- scan step 2: exclusive-scan the 98 block sums ----------------
__global__ void k_scan2(int* __restrict__ bsum) {
  if (blockIdx.x == 0 && threadIdx.x == 0) {
    int run = 0;
    for (int b = 0; b < NB; ++b) { int v = bsum[b]; bsum[b] = run; run += v; }
  }
}

// ---------------- scan step 3: rowptr ----------------
__global__ void k_scan3(const int* __restrict__ tmp, const int* __restrict__ bsum,
                        int* __restrict__ rowptr) {
  int t = threadIdx.x;
  int i = blockIdx.x * 1024 + t;
  if (i >= NN) return;
  rowptr[i + 1] = tmp[i] + bsum[blockIdx.x];
  if (i == 0) rowptr[0] = 0;
}

// ---------------- partition pass 1: per-(block,bucket) counts ----------------
__global__ void k_cnt(const int* __restrict__ dst, int* __restrict__ counts) {
  __shared__ int c[NBK];
  int blk = blockIdx.x, t = threadIdx.x;
  for (int i = t; i < NBK; i += blockDim.x) c[i] = 0;
  __syncthreads();
  int e0 = blk * EPB;
  for (int e = e0 + t; e < e0 + EPB; e += blockDim.x)
    atomicAdd(&c[dst[e] >> 8], 1);
  __syncthreads();
  for (int i = t; i < NBK; i += blockDim.x) counts[i * NBLK + blk] = c[i];
}

// ---------------- partition pass 2: per-bucket exclusive scan over blocks ----------------
// one block per bucket; NBLK==blockDim==512
__global__ void k_bofs(const int* __restrict__ counts, const int* __restrict__ rowptr,
                       int* __restrict__ offs) {
  __shared__ int s[NBLK];
  int b = blockIdx.x, t = threadIdx.x;
  int own = counts[b * NBLK + t];
  s[t] = own;
  __syncthreads();
  for (int off = 1; off < NBLK; off <<= 1) {
    int add = (t >= off) ? s[t - off] : 0;
    __syncthreads();
    s[t] += add;
    __syncthreads();
  }
  offs[b * NBLK + t] = rowptr[b << 8] + s[t] - own;
}

// ---------------- partition pass 3: LDS counting sort + segment-contiguous write ----------------
__global__ void __launch_bounds__(512) k_bwrite(const int* __restrict__ src,
                                                const int* __restrict__ dst,
                                                const int* __restrict__ offs,
                                                unsigned int* __restrict__ ebuf) {
  __shared__ unsigned int stage[EPB];       // 25000 B
  __shared__ unsigned short bstage[EPB];    // 12500 B
  __shared__ int cnt[NBK];                  // 1564 B
  __shared__ int sc[NBLK];                  // 2048 B (inclusive scan wkspace)
  __shared__ int cur[NBK];                  // 1564 B
  __shared__ int obase[NBK];                // 1564 B
  int blk = blockIdx.x, t = threadIdx.x;
  int e0 = blk * EPB;

  for (int i = t; i < NBK; i += blockDim.x) cnt[i] = 0;
  __syncthreads();
  // pass 1: local bucket histogram
  for (int e = e0 + t; e < e0 + EPB; e += blockDim.x)
    atomicAdd(&cnt[dst[e] >> 8], 1);
  __syncthreads();
  // inclusive scan of cnt (padded to 512)
  int own = (t < NBK) ? cnt[t] : 0;
  sc[t] = own;
  __syncthreads();
  for (int off = 1; off < NBLK; off <<= 1) {
    int add = (t >= off) ? sc[t - off] : 0;
    __syncthreads();
    sc[t] += add;
    __syncthreads();
  }
  if (t < NBK) {
    cur[t] = sc[t] - own;               // exclusive base = local cursor init
    obase[t] = offs[t * NBLK + blk];    // global segment base for this block
  }
  __syncthreads();
  // pass 2: scatter into LDS stage (counting sort, order-irrelevant)
  for (int e = e0 + t; e < e0 + EPB; e += blockDim.x) {
    int d = dst[e];
    int b = d >> 8;
    int p = atomicAdd(&cur[b], 1);
    stage[p] = ((unsigned int)src[e] << 8) | (unsigned int)(d & 255);
    bstage[p] = (unsigned short)b;
  }
  __syncthreads();
  // pass 3: stream out; consecutive i in a bucket -> consecutive global slots
  for (int i = t; i < EPB; i += blockDim.x) {
    int b = (int)bstage[i];
    int local_excl = sc[b] - cnt[b];
    ebuf[obase[b] + (i - local_excl)] = stage[i];
  }
}

// ---------------- bucket fill: LDS per-node cursors, local csr writes ----------------
__global__ void k_bfill(const int* __restrict__ rowptr, const unsigned int* __restrict__ ebuf,
                        int* __restrict__ csr_src) {
  __shared__ int cur[256];
  int b = blockIdx.x;
  int t = threadIdx.x;
  int nfirst = b << 8;
  int ncount = min(256, NN - nfirst);
  if (t < ncount) cur[t] = rowptr[nfirst + t];
  __syncthreads();
  int beg = rowptr[nfirst];
  int end = rowptr[nfirst + ncount];
  for (int j = beg + t; j < end; j += blockDim.x) {
    unsigned int v = ebuf[j];
    int pos = atomicAdd(&cur[v & 255u], 1);
    csr_src[pos] = (int)(v >> 8);
  }
}

// ---------------- G1: per-node gather, exact f64 accumulate, sign -> int8 ----------------
__global__ void k_gather1(const int* __restrict__ rowptr, const int* __restrict__ csr_src,
                          const float* __restrict__ h0f, signed char* __restrict__ h1) {
  int g = blockIdx.x * blockDim.x + threadIdx.x;
  int n = g >> 6;
  int lane = g & 63;
  if (n >= NN) return;
  int beg = rowptr[n], end = rowptr[n + 1];
  double acc = (double)h0f[n * DD + lane];  // self-loop
  int j = beg;
  for (; j + 4 <= end; j += 4) {
    int s0 = csr_src[j], s1 = csr_src[j + 1], s2 = csr_src[j + 2], s3 = csr_src[j + 3];
    float v0 = h0f[s0 * DD + lane];
    float v1 = h0f[s1 * DD + lane];
    float v2 = h0f[s2 * DD + lane];
    float v3 = h0f[s3 * DD + lane];
    acc += (double)v0; acc += (double)v1; acc += (double)v2; acc += (double)v3;
  }
  for (; j < end; ++j) acc += (double)h0f[csr_src[j] * DD + lane];
  h1[n * DD + lane] = (acc > 0.0) ? 1 : ((acc < 0.0) ? -1 : 0);
}

// ---------------- G2: per-node int gather + sign + partitionable-threefry dropout ----------------
__global__ void k_gather2(const int* __restrict__ rowptr, const int* __restrict__ csr_src,
                          const signed char* __restrict__ h1, float* __restrict__ out2) {
  int g = blockIdx.x * blockDim.x + threadIdx.x;
  int n = g >> 6;
  int lane = g & 63;
  if (n >= NN) return;
  int beg = rowptr[n], end = rowptr[n + 1];
  int acc = (int)h1[n * DD + lane];  // self-loop
  int j = beg;
  for (; j + 4 <= end; j += 4) {
    int s0 = csr_src[j], s1 = csr_src[j + 1], s2 = csr_src[j + 2], s3 = csr_src[j + 3];
    acc += (int)h1[s0 * DD + lane] + (int)h1[s1 * DD + lane]
         + (int)h1[s2 * DD + lane] + (int)h1[s3 * DD + lane];
  }
  for (; j < end; ++j) acc += (int)h1[csr_src[j] * DD + lane];

  int i = n * DD + lane;
  float s = (acc > 0) ? 1.0f : ((acc < 0) ? -1.0f : 0.0f);
  unsigned int o0, o1;
  threefry2x32_0_42(0u, (unsigned int)i, o0, o1);
  unsigned int bits = o0 ^ o1;
  const float inv_keep = 1.0f / 0.9f;
  out2[i] = keep_from_bits(bits) ? s * inv_keep : 0.0f;
}

extern "C" void kernel_launch(void* const* d_in, const int* in_sizes, int n_in,
                              void* d_out, int out_size, void* d_ws, size_t ws_size,
                              hipStream_t stream) {
  const float* x   = (const float*)d_in[0];
  const int*   ei  = (const int*)d_in[1];
  const int*   src = ei;        // edge_index[0]
  const int*   dst = ei + NE;   // edge_index[1]

  float* out_h  = (float*)d_out;           // output 0: h    [ELEMS]
  float* out_h2 = (float*)d_out + ELEMS;   // output 1: h_2  [ELEMS]

  char* ws = (char*)d_ws;
  float*        h0f     = (float*)ws;                              // 25.6 MB @ 0
  signed char*  h1      = (signed char*)(ws + ((size_t)26 << 20)); // 6.4 MB  @ 26M
  int*          deg     = (int*)(ws + ((size_t)33 << 20));         // 400 KB
  int*          tmp     = (int*)(ws + ((size_t)34 << 20));         // 400 KB
  int*          bsum    = (int*)(ws + ((size_t)35 << 20));         // <1 KB
  int*          rowptr  = (int*)(ws + ((size_t)36 << 20));         // 400 KB + 4
  int*          csr_src = (int*)(ws + ((size_t)38 << 20));         // 12.8 MB
  unsigned int* ebuf    = (unsigned int*)(ws + ((size_t)51 << 20));// 12.8 MB
  int*          counts  = (int*)(ws + ((size_t)64 << 20));         // 800 KB
  int*          offs    = (int*)(ws + ((size_t)65 << 20));         // 800 KB

  const int B = 256;
  const int gElems = (ELEMS + B - 1) / B;          // 25000
  const int gEdges = (NE + B - 1) / B;             // 12500

  (void)hipMemsetAsync(deg, 0, (size_t)NN * sizeof(int), stream);

  kA<<<gElems, B, 0, stream>>>(x, out_h, h0f);

  k_hist<<<gEdges, B, 0, stream>>>(dst, deg);
  k_scan1<<<NB, 1024, 0, stream>>>(deg, tmp, bsum);
  k_scan2<<<1, 64, 0, stream>>>(bsum);
  k_scan3<<<NB, 1024, 0, stream>>>(tmp, bsum, rowptr);

  k_cnt<<<NBLK, B, 0, stream>>>(dst, counts);
  k_bofs<<<NBK, NBLK, 0, stream>>>(counts, rowptr, offs);
  k_bwrite<<<NBLK, NBLK, 0, stream>>>(src, dst, offs, ebuf);
  k_bfill<<<NBK, B, 0, stream>>>(rowptr, ebuf, csr_src);

  k_gather1<<<gElems, B, 0, stream>>>(rowptr, csr_src, h0f, h1);
  k_gather2<<<gElems, B, 0, stream>>>(rowptr, csr_src, h1, out_h2);
}

// Round 8
// 374.239 us; speedup vs baseline: 4.2183x; 1.3344x over previous
//
#include <hip/hip_runtime.h>

#define NN 100000
#define NE 3200000
#define DD 64

constexpr int ELEMS = NN * DD;            // 6,400,000
constexpr int NBK   = (NN + 255) / 256;   // 391 buckets of 256 nodes
constexpr int NBLK  = 512;                // partition blocks
constexpr int EPB   = NE / NBLK;          // 6250 edges per block (exact)

// ---------------- Threefry-2x32, key = (0, 42), 20 rounds ----------------
__device__ __forceinline__ void threefry2x32_0_42(unsigned int c0, unsigned int c1,
                                                  unsigned int& o0, unsigned int& o1) {
  const unsigned int ks0 = 0u;
  const unsigned int ks1 = 42u;
  const unsigned int ks2 = ks0 ^ ks1 ^ 0x1BD11BDAu;
  unsigned int x0 = c0 + ks0;
  unsigned int x1 = c1 + ks1;
#define TF_R(r) { x0 += x1; x1 = (x1 << (r)) | (x1 >> (32 - (r))); x1 ^= x0; }
  TF_R(13) TF_R(15) TF_R(26) TF_R(6)
  x0 += ks1; x1 += ks2 + 1u;
  TF_R(17) TF_R(29) TF_R(16) TF_R(24)
  x0 += ks2; x1 += ks0 + 2u;
  TF_R(13) TF_R(15) TF_R(26) TF_R(6)
  x0 += ks0; x1 += ks1 + 3u;
  TF_R(17) TF_R(29) TF_R(16) TF_R(24)
  x0 += ks1; x1 += ks2 + 4u;
  TF_R(13) TF_R(15) TF_R(26) TF_R(6)
  x0 += ks2; x1 += ks0 + 5u;
#undef TF_R
  o0 = x0; o1 = x1;
}

__device__ __forceinline__ bool keep_from_bits(unsigned int bits) {
  float f = __uint_as_float((bits >> 9) | 0x3f800000u) - 1.0f;
  return f < 0.9f;
}

// ---------------- A: h = sign(x); h0f = tanh(x) ----------------
__global__ void kA(const float* __restrict__ x,
                   float* __restrict__ h_out,
                   float* __restrict__ h0f) {
  int i = blockIdx.x * blockDim.x + threadIdx.x;
  if (i >= ELEMS) return;
  float xv = x[i];
  h0f[i] = (float)tanh((double)xv);
  h_out[i] = (xv > 0.0f) ? 1.0f : ((xv < 0.0f) ? -1.0f : 0.0f);
}

// ---------------- partition pass 1: per-(block,bucket) counts ----------------
__global__ void k_cnt(const int* __restrict__ dst, int* __restrict__ counts) {
  __shared__ int c[NBK];
  int blk = blockIdx.x, t = threadIdx.x;
  for (int i = t; i < NBK; i += blockDim.x) c[i] = 0;
  __syncthreads();
  int e0 = blk * EPB;
  for (int e = e0 + t; e < e0 + EPB; e += blockDim.x)
    atomicAdd(&c[dst[e] >> 8], 1);
  __syncthreads();
  for (int i = t; i < NBK; i += blockDim.x) counts[i * NBLK + blk] = c[i];
}

// ---------------- partition pass 2: per-bucket exclusive scan over blocks + totals ----------------
// one block per bucket; blockDim == NBLK == 512
__global__ void k_bofs(const int* __restrict__ counts,
                       int* __restrict__ offs_local, int* __restrict__ btot) {
  __shared__ int s[NBLK];
  int b = blockIdx.x, t = threadIdx.x;
  int own = counts[b * NBLK + t];
  s[t] = own;
  __syncthreads();
  for (int off = 1; off < NBLK; off <<= 1) {
    int add = (t >= off) ? s[t - off] : 0;
    __syncthreads();
    s[t] += add;
    __syncthreads();
  }
  offs_local[b * NBLK + t] = s[t] - own;   // exclusive within bucket
  if (t == NBLK - 1) btot[b] = s[t];       // bucket total
}

// ---------------- bucket bases: exclusive scan of 391 totals (1 block, 512 thr) ----------------
__global__ void k_bbase(const int* __restrict__ btot, int* __restrict__ bbase) {
  __shared__ int s[NBLK];
  int t = threadIdx.x;
  int own = (t < NBK) ? btot[t] : 0;
  s[t] = own;
  __syncthreads();
  for (int off = 1; off < NBLK; off <<= 1) {
    int add = (t >= off) ? s[t - off] : 0;
    __syncthreads();
    s[t] += add;
    __syncthreads();
  }
  if (t < NBK) bbase[t] = s[t] - own;
  if (t == 0) bbase[NBK] = NE;
}

// ---------------- partition pass 3: LDS counting sort + segment-contiguous write ----------------
__global__ void __launch_bounds__(512) k_bwrite(const int* __restrict__ src,
                                                const int* __restrict__ dst,
                                                const int* __restrict__ offs_local,
                                                const int* __restrict__ bbase,
                                                unsigned int* __restrict__ ebuf) {
  __shared__ unsigned int stage[EPB];       // 25000 B
  __shared__ unsigned short bstage[EPB];    // 12500 B
  __shared__ int cnt[NBK];
  __shared__ int sc[NBLK];
  __shared__ int cur[NBK];
  __shared__ int obase[NBK];
  int blk = blockIdx.x, t = threadIdx.x;
  int e0 = blk * EPB;

  for (int i = t; i < NBK; i += blockDim.x) cnt[i] = 0;
  __syncthreads();
  for (int e = e0 + t; e < e0 + EPB; e += blockDim.x)
    atomicAdd(&cnt[dst[e] >> 8], 1);
  __syncthreads();
  int own = (t < NBK) ? cnt[t] : 0;
  sc[t] = own;
  __syncthreads();
  for (int off = 1; off < NBLK; off <<= 1) {
    int add = (t >= off) ? sc[t - off] : 0;
    __syncthreads();
    sc[t] += add;
    __syncthreads();
  }
  if (t < NBK) {
    cur[t] = sc[t] - own;
    obase[t] = bbase[t] + offs_local[t * NBLK + blk];
  }
  __syncthreads();
  for (int e = e0 + t; e < e0 + EPB; e += blockDim.x) {
    int d = dst[e];
    int b = d >> 8;
    int p = atomicAdd(&cur[b], 1);
    stage[p] = ((unsigned int)src[e] << 8) | (unsigned int)(d & 255);
    bstage[p] = (unsigned short)b;
  }
  __syncthreads();
  for (int i = t; i < EPB; i += blockDim.x) {
    int b = (int)bstage[i];
    int local_excl = sc[b] - cnt[b];
    ebuf[obase[b] + (i - local_excl)] = stage[i];
  }
}

// ---------------- fused: per-bucket node histogram -> rowptr + csr fill ----------------
// one 256-thread block per bucket; segment [bbase[b], bbase[b+1]) of ebuf
__global__ void k_fill(const int* __restrict__ bbase, const unsigned int* __restrict__ ebuf,
                       int* __restrict__ rowptr, int* __restrict__ csr_src) {
  __shared__ int cnt[256];
  __shared__ int sc[256];
  __shared__ int cur[256];
  int b = blockIdx.x;
  int t = threadIdx.x;
  int seg_beg = bbase[b];
  int seg_end = bbase[b + 1];
  int nfirst = b << 8;
  int ncount = min(256, NN - nfirst);

  cnt[t] = 0;
  __syncthreads();
  // pass 1: histogram over 256 node slots
  for (int j = seg_beg + t; j < seg_end; j += 256)
    atomicAdd(&cnt[ebuf[j] & 255u], 1);
  __syncthreads();
  // inclusive scan
  int own = cnt[t];
  sc[t] = own;
  __syncthreads();
  for (int off = 1; off < 256; off <<= 1) {
    int add = (t >= off) ? sc[t - off] : 0;
    __syncthreads();
    sc[t] += add;
    __syncthreads();
  }
  // rowptr + cursors
  if (t < ncount) {
    rowptr[nfirst + t + 1] = seg_beg + sc[t];
    cur[t] = seg_beg + sc[t] - own;
  }
  if (b == 0 && t == 0) rowptr[0] = 0;
  __syncthreads();
  // pass 2: scatter into csr (local region, L2-resident)
  for (int j = seg_beg + t; j < seg_end; j += 256) {
    unsigned int v = ebuf[j];
    int pos = atomicAdd(&cur[v & 255u], 1);
    csr_src[pos] = (int)(v >> 8);
  }
}

// ---------------- G1: per-node gather, exact f64 accumulate, sign -> int8 ----------------
__global__ void k_gather1(const int* __restrict__ rowptr, const int* __restrict__ csr_src,
                          const float* __restrict__ h0f, signed char* __restrict__ h1) {
  int g = blockIdx.x * blockDim.x + threadIdx.x;
  int n = g >> 6;
  int lane = g & 63;
  if (n >= NN) return;
  int beg = rowptr[n], end = rowptr[n + 1];
  double acc = (double)h0f[n * DD + lane];  // self-loop
  int j = beg;
  for (; j + 4 <= end; j += 4) {
    int s0 = csr_src[j], s1 = csr_src[j + 1], s2 = csr_src[j + 2], s3 = csr_src[j + 3];
    float v0 = h0f[s0 * DD + lane];
    float v1 = h0f[s1 * DD + lane];
    float v2 = h0f[s2 * DD + lane];
    float v3 = h0f[s3 * DD + lane];
    acc += (double)v0; acc += (double)v1; acc += (double)v2; acc += (double)v3;
  }
  for (; j < end; ++j) acc += (double)h0f[csr_src[j] * DD + lane];
  h1[n * DD + lane] = (acc > 0.0) ? 1 : ((acc < 0.0) ? -1 : 0);
}

// ---------------- G2: per-node int gather + sign + partitionable-threefry dropout ----------------
__global__ void k_gather2(const int* __restrict__ rowptr, const int* __restrict__ csr_src,
                          const signed char* __restrict__ h1, float* __restrict__ out2) {
  int g = blockIdx.x * blockDim.x + threadIdx.x;
  int n = g >> 6;
  int lane = g & 63;
  if (n >= NN) return;
  int beg = rowptr[n], end = rowptr[n + 1];
  int acc = (int)h1[n * DD + lane];  // self-loop
  int j = beg;
  for (; j + 4 <= end; j += 4) {
    int s0 = csr_src[j], s1 = csr_src[j + 1], s2 = csr_src[j + 2], s3 = csr_src[j + 3];
    acc += (int)h1[s0 * DD + lane] + (int)h1[s1 * DD + lane]
         + (int)h1[s2 * DD + lane] + (int)h1[s3 * DD + lane];
  }
  for (; j < end; ++j) acc += (int)h1[csr_src[j] * DD + lane];

  int i = n * DD + lane;
  float s = (acc > 0) ? 1.0f : ((acc < 0) ? -1.0f : 0.0f);
  unsigned int o0, o1;
  threefry2x32_0_42(0u, (unsigned int)i, o0, o1);
  unsigned int bits = o0 ^ o1;
  const float inv_keep = 1.0f / 0.9f;
  out2[i] = keep_from_bits(bits) ? s * inv_keep : 0.0f;
}

extern "C" void kernel_launch(void* const* d_in, const int* in_sizes, int n_in,
                              void* d_out, int out_size, void* d_ws, size_t ws_size,
                              hipStream_t stream) {
  const float* x   = (const float*)d_in[0];
  const int*   ei  = (const int*)d_in[1];
  const int*   src = ei;        // edge_index[0]
  const int*   dst = ei + NE;   // edge_index[1]

  float* out_h  = (float*)d_out;           // output 0: h    [ELEMS]
  float* out_h2 = (float*)d_out + ELEMS;   // output 1: h_2  [ELEMS]

  char* ws = (char*)d_ws;
  float*        h0f        = (float*)ws;                              // 25.6 MB @ 0
  signed char*  h1         = (signed char*)(ws + ((size_t)26 << 20)); // 6.4 MB  @ 26M
  int*          rowptr     = (int*)(ws + ((size_t)33 << 20));         // 400 KB + 4
  int*          bbase      = (int*)(ws + ((size_t)34 << 20));         // 1.6 KB
  int*          btot       = (int*)(ws + ((size_t)35 << 20));         // 1.6 KB
  int*          counts     = (int*)(ws + ((size_t)36 << 20));         // 800 KB
  int*          offs_local = (int*)(ws + ((size_t)37 << 20));         // 800 KB
  int*          csr_src    = (int*)(ws + ((size_t)38 << 20));         // 12.8 MB
  unsigned int* ebuf       = (unsigned int*)(ws + ((size_t)51 << 20));// 12.8 MB

  const int B = 256;
  const int gElems = (ELEMS + B - 1) / B;          // 25000

  kA<<<gElems, B, 0, stream>>>(x, out_h, h0f);

  k_cnt<<<NBLK, B, 0, stream>>>(dst, counts);
  k_bofs<<<NBK, NBLK, 0, stream>>>(counts, offs_local, btot);
  k_bbase<<<1, NBLK, 0, stream>>>(btot, bbase);
  k_bwrite<<<NBLK, NBLK, 0, stream>>>(src, dst, offs_local, bbase, ebuf);
  k_fill<<<NBK, B, 0, stream>>>(bbase, ebuf, rowptr, csr_src);

  k_gather1<<<gElems, B, 0, stream>>>(rowptr, csr_src, h0f, h1);
  k_gather2<<<gElems, B, 0, stream>>>(rowptr, csr_src, h1, out_h2);
}